// Round 8
// baseline (867.012 us; speedup 1.0000x reference)
//
#include <hip/hip_runtime.h>
#include <hip/hip_bf16.h>
#include <stdint.h>
#include <stddef.h>

typedef float  f32x4  __attribute__((ext_vector_type(4)));
typedef float  f32x16 __attribute__((ext_vector_type(16)));
typedef int    i32x8  __attribute__((ext_vector_type(8)));
typedef unsigned char u8;

#define LOG2E  1.44269504f
#define QSCALE 0.18033688f      /* 0.125 * log2(e) */
#define WSC    16.0f            /* weight prescale before fp8 cast */
#define IWSC   0.0625f
#define QSTORE 0.36067376f      /* QSCALE * 32 / 16 : gemm-acc -> q_fp8 */
#define KSTORE 0.5f             /* 8 / 16          : gemm-acc -> k_fp8 */
#define SCALE_A_M8 0x77777777   /* e8m0 119 = 2^-8 (undo 32*8) */
#define SCALE_ONE  0x7F7F7F7F   /* e8m0 127 = 1.0 */

// ---------------------------------------------------------------- helpers
__device__ __forceinline__ void gld_lds16(const void* gptr, void* lptr) {
    __builtin_amdgcn_global_load_lds(
        (const __attribute__((address_space(1))) unsigned int*)gptr,
        (__attribute__((address_space(3))) unsigned int*)lptr,
        16, 0, 0);
}

// ---------------------------------------------------------------- merged cast + zero
// fp8 e4m3. blocks [0,6144): g (x1) ; [6144,6720): wq ; [6720,7296): wk ;
// [7296,9600): w_hn (weights x16). blocks [0,104) zero sums (106496 f32);
// block 0 thread 0 zeroes out[0].
__global__ void cast_all(const float* __restrict__ g, const float* __restrict__ wq,
                         const float* __restrict__ wk, const float* __restrict__ whn,
                         u8* __restrict__ g_f8, u8* __restrict__ Wcat,
                         float* __restrict__ sums, float* __restrict__ out) {
    int b = blockIdx.x, t = threadIdx.x;
    if (b < 104) {
        float4 z = {0.f, 0.f, 0.f, 0.f};
        *(float4*)(sums + (b * 256 + t) * 4) = z;
        if (b == 0 && t == 0) out[0] = 0.f;
    }
    const float* src; u8* dst; int off; float sc;
    if (b < 6144)      { src = g;   dst = g_f8;           off = 0;    sc = 1.0f; }
    else if (b < 6720) { src = wq;  dst = Wcat;           off = 6144; sc = WSC;  }
    else if (b < 7296) { src = wk;  dst = Wcat + 589824;  off = 6720; sc = WSC;  }
    else               { src = whn; dst = Wcat + 1179648; off = 7296; sc = WSC;  }
    int i = ((b - off) * 256 + t) * 4;
    float4 v = *(const float4*)(src + i);
    int p = __builtin_amdgcn_cvt_pk_fp8_f32(sc * v.x, sc * v.y, 0, false);
    p     = __builtin_amdgcn_cvt_pk_fp8_f32(sc * v.z, sc * v.w, p, true);
    *(int*)(dst + i) = p;
}

// ---------------------------------------------------------------- fused NT GEMM (MX-fp8)
// C_full[M,4608] = A[M,768] * Wcat[4608,768]^T, fp8 e4m3, fp32 acc.
// mfma_scale_f32_16x16x128_f8f6f4, unit scales. BM=BN=128, BK=128.
// cols [0,1536): q/k -> fp8 qkh[b][h][{q,k}] planes of 1024x64 B with SUPER-ROW
//   swizzle: u=kr>>1, sigma=(kr&1)*4+(z>>4), pos = u*128 + (sigma^(u&7))*16 + (z&15).
//   q scaled QSTORE, k scaled KSTORE (fold attn beta + fp8 range centering).
// cols [1536,4608): Hopfield -> rowsum += exp2(beta*log2e/16 * acc) via atomicAdd.
__global__ void gemm_fused(const u8* __restrict__ A, const u8* __restrict__ Bm,
                           u8* __restrict__ qkh, float* __restrict__ rowsum,
                           const float* __restrict__ beta_p) {
    __shared__ __align__(16) u8 As[128 * 128];
    __shared__ __align__(16) u8 Bs[128 * 128];
    const int t = threadIdx.x;
    const int w = t >> 6, l = t & 63;
    const int wm = (w >> 1) * 64, wn = (w & 1) * 64;
    const int tile_m = blockIdx.x * 128;
    const int tile_n = blockIdx.y * 128;

    f32x4 acc[4][4];
#pragma unroll
    for (int i = 0; i < 4; i++)
#pragma unroll
        for (int j = 0; j < 4; j++)
#pragma unroll
            for (int q = 0; q < 4; q++) acc[i][j][q] = 0.f;

    const int srow = t >> 3;
    const int sswz = (t & 7) ^ (srow & 7);
    const u8* gA = A  + (size_t)(tile_m + srow) * 768 + sswz * 16;
    const u8* gB = Bm + (size_t)(tile_n + srow) * 768 + sswz * 16;

    const int fr = l & 15, fg = l >> 4;
    const int s0 = ((2 * fg)     ^ (fr & 7)) * 16;
    const int s1 = ((2 * fg + 1) ^ (fr & 7)) * 16;

    for (int k0 = 0; k0 < 768; k0 += 128) {
#pragma unroll
        for (int i = 0; i < 4; i++) {
            gld_lds16(gA + (size_t)i * 32 * 768 + k0, As + (i * 256 + t) * 16);
            gld_lds16(gB + (size_t)i * 32 * 768 + k0, Bs + (i * 256 + t) * 16);
        }
        __builtin_amdgcn_s_waitcnt(0);
        __syncthreads();

        union F8 { uint4 q[2]; i32x8 v; };
        i32x8 af[4], bfr[4];
#pragma unroll
        for (int i = 0; i < 4; i++) {
            const u8* ra = As + (wm + i * 16 + fr) * 128;
            const u8* rb = Bs + (wn + i * 16 + fr) * 128;
            F8 ua, ub;
            ua.q[0] = *(const uint4*)(ra + s0);
            ua.q[1] = *(const uint4*)(ra + s1);
            ub.q[0] = *(const uint4*)(rb + s0);
            ub.q[1] = *(const uint4*)(rb + s1);
            af[i] = ua.v; bfr[i] = ub.v;
        }
#pragma unroll
        for (int i = 0; i < 4; i++)
#pragma unroll
            for (int j = 0; j < 4; j++)
                acc[i][j] = __builtin_amdgcn_mfma_scale_f32_16x16x128_f8f6f4(
                    af[i], bfr[j], acc[i][j], 0, 0, 0, SCALE_ONE, 0, SCALE_ONE);
        __syncthreads();
    }

    const int cr = fg * 4, cc = fr;

    if (tile_n < 1536) {
        const int tt = (tile_n >= 768);
        const int hh = (tile_n - tt * 768 + wn) >> 6;
        const int bb = tile_m >> 10;
        const int m7 = tile_m & 1023;
        const float sc = tt ? KSTORE : QSTORE;
        u8* base = qkh + ((size_t)((bb * 12 + hh) * 2 + tt) << 16);
#pragma unroll
        for (int i = 0; i < 4; i++)
#pragma unroll
            for (int r = 0; r < 4; r++) {
                int kr = m7 + wm + i * 16 + cr + r;
                int u = kr >> 1, p4 = (kr & 1) * 4, u7 = u & 7;
                u8* rowp = base + (size_t)u * 128;
#pragma unroll
                for (int j = 0; j < 4; j++) {
                    int pv = __builtin_amdgcn_cvt_pk_fp8_f32(sc * acc[i][j][r], 0.f, 0, false);
                    rowp[((p4 + j) ^ u7) * 16 + cc] = (u8)(pv & 0xFF);
                }
            }
    } else {
        const float sc2 = beta_p[0] * LOG2E * IWSC;
#pragma unroll
        for (int i = 0; i < 4; i++)
#pragma unroll
            for (int r = 0; r < 4; r++) {
                float s = 0.f;
#pragma unroll
                for (int j = 0; j < 4; j++) s += __builtin_amdgcn_exp2f(sc2 * acc[i][j][r]);
                s += __shfl_xor(s, 1, 16);
                s += __shfl_xor(s, 2, 16);
                s += __shfl_xor(s, 4, 16);
                s += __shfl_xor(s, 8, 16);
                if ((l & 15) == 0)
                    atomicAdd(&rowsum[tile_m + wm + i * 16 + cr + r], s);
            }
    }
}

// ---------------------------------------------------------------- attention exp-sums
// qkh fp8 planes (super-row swizzled). grid (qt*2+kh:16, h:12, b:8), 256 thr.
// Block: 128 q-rows x 512 K-rows via mfma_scale_f32_32x32x64_f8f6f4 (whole Z=64
// contraction per instruction). scale_a = 2^-8 folds the stored q/k gains so
// acc = beta*log2e*(q.k) directly -> rs += exp2(acc), no VALU pre-multiply.
// Q tile 8 KB staged once; K in double-buffered 8 KB chunks (linear gld16).
__global__ void __launch_bounds__(256, 6)
attn_energy(const u8* __restrict__ qkh, float* __restrict__ arow) {
    __shared__ __align__(16) u8 Sq[8192];
    __shared__ __align__(16) u8 Sk[2][8192];
    const int t = threadIdx.x, w = t >> 6, l = t & 63;
    const int qt = blockIdx.x >> 1, kh = blockIdx.x & 1;
    const int h = blockIdx.y, b = blockIdx.z;
    const u8* qp = qkh + ((size_t)((b * 12 + h) * 2 + 0) << 16) + qt * 8192;
    const u8* kp = qkh + ((size_t)((b * 12 + h) * 2 + 1) << 16) + kh * 32768;

    gld_lds16(qp + t * 16,        Sq + t * 16);
    gld_lds16(qp + 4096 + t * 16, Sq + 4096 + t * 16);
    gld_lds16(kp + t * 16,        Sk[0] + t * 16);
    gld_lds16(kp + 4096 + t * 16, Sk[0] + 4096 + t * 16);
    __builtin_amdgcn_s_waitcnt(0);
    __syncthreads();

    const int ln = l & 31, lh = l >> 5;
    union F8x32 { uint4 q[2]; i32x8 v; };

    // A fragment: row rA = w*32+ln, k-bytes [32*lh, +32) = segs {p4+2lh, p4+2lh+1}
    const int rA = w * 32 + ln, uA = rA >> 1, u7A = uA & 7;
    const int sA = (rA & 1) * 4 + lh * 2;
    F8x32 ua;
    ua.q[0] = *(const uint4*)(Sq + uA * 128 + ((sA)     ^ u7A) * 16);
    ua.q[1] = *(const uint4*)(Sq + uA * 128 + ((sA + 1) ^ u7A) * 16);

    float rs[16];
#pragma unroll
    for (int r = 0; r < 16; r++) rs[r] = 0.f;

    for (int kc = 0; kc < 4; kc++) {
        const u8* Sc = Sk[kc & 1];
        __builtin_amdgcn_s_waitcnt(0);
        __syncthreads();
        if (kc < 3) {
            const u8* src = kp + (kc + 1) * 8192;
            u8* d = (u8*)Sk[1 - (kc & 1)];
            gld_lds16(src + t * 16,        d + t * 16);
            gld_lds16(src + 4096 + t * 16, d + 4096 + t * 16);
        }
#pragma unroll
        for (int nt = 0; nt < 4; nt++) {
            const int rB = nt * 32 + ln, uB = rB >> 1, u7B = uB & 7;
            const int sB = (rB & 1) * 4 + lh * 2;
            F8x32 ub;
            ub.q[0] = *(const uint4*)(Sc + uB * 128 + ((sB)     ^ u7B) * 16);
            ub.q[1] = *(const uint4*)(Sc + uB * 128 + ((sB + 1) ^ u7B) * 16);
            f32x16 acc;
#pragma unroll
            for (int q = 0; q < 16; q++) acc[q] = 0.f;
            acc = __builtin_amdgcn_mfma_scale_f32_32x32x64_f8f6f4(
                ua.v, ub.v, acc, 0, 0, 0, SCALE_A_M8, 0, SCALE_ONE);
#pragma unroll
            for (int r = 0; r < 16; r++) rs[r] += __builtin_amdgcn_exp2f(acc[r]);
        }
    }

    // D layout (32x32): col=lane&31 (k-col), row=(r&3)+8*(r>>2)+4*lh (q-row).
    // Reduce over 32 k-lanes; 2 kh-writers per row -> atomicAdd.
    const int rowbase = (b * 12 + h) * 1024 + qt * 128 + w * 32 + lh * 4;
#pragma unroll
    for (int r = 0; r < 16; r++) {
        float v = rs[r];
        v += __shfl_xor(v, 1, 32);
        v += __shfl_xor(v, 2, 32);
        v += __shfl_xor(v, 4, 32);
        v += __shfl_xor(v, 8, 32);
        v += __shfl_xor(v, 16, 32);
        if (ln == 0)
            atomicAdd(&arow[rowbase + (r & 3) + 8 * (r >> 2)], v);
    }
}

// ---------------------------------------------------------------- merged finalize
__global__ void finalize(const float* __restrict__ sums, const float* __restrict__ beta_p,
                         float* __restrict__ out) {
    __shared__ float wpart[4];
    const int t = threadIdx.x, w = t >> 6, l = t & 63;
    const int i = blockIdx.x * 256 + t;
    float v;
    if (i < 8192) v = (-1.f / beta_p[0]) * __logf(sums[i]);
    else          v = -8.f * __logf(sums[i]);
    for (int o = 32; o > 0; o >>= 1) v += __shfl_down(v, o, 64);
    if (l == 0) wpart[w] = v;
    __syncthreads();
    if (t == 0) atomicAdd(out, wpart[0] + wpart[1] + wpart[2] + wpart[3]);
}

// ---------------------------------------------------------------- launch
extern "C" void kernel_launch(void* const* d_in, const int* in_sizes, int n_in,
                              void* d_out, int out_size, void* d_ws, size_t ws_size,
                              hipStream_t stream) {
    const float* g    = (const float*)d_in[0];
    const float* wq   = (const float*)d_in[1];
    const float* wk   = (const float*)d_in[2];
    const float* w_hn = (const float*)d_in[3];
    const float* beta = (const float*)d_in[4];
    float* out = (float*)d_out;

    char* ws = (char*)d_ws;
    u8*    g_f8   = (u8*)(ws);                    //  6,291,456 B
    u8*    Wcat   = (u8*)(ws + 6291456);          //  3,538,944 B
    u8*    qkh    = (u8*)(ws + 9830400);          // 12,582,912 B [8][12][2] 64KB planes
    float* sums   = (float*)(ws + 22413312);      // rowsum 8192 | arow 98304
    float* rowsum = sums;
    float* arow   = sums + 8192;

    cast_all<<<9600, 256, 0, stream>>>(g, wq, wk, w_hn, g_f8, Wcat, sums, out);

    dim3 gg(64, 36);
    gemm_fused<<<gg, 256, 0, stream>>>(g_f8, Wcat, qkh, rowsum, beta);

    dim3 ga(16, 12, 8);   // (qt,kh), h, b
    attn_energy<<<ga, 256, 0, stream>>>(qkh, arow);

    finalize<<<416, 256, 0, stream>>>(sums, beta, out);
}

// Round 9
// 149.635 us; speedup vs baseline: 5.7942x; 5.7942x over previous
//
#include <hip/hip_runtime.h>
#include <hip/hip_bf16.h>
#include <stdint.h>
#include <stddef.h>

typedef float  f32x4  __attribute__((ext_vector_type(4)));
typedef float  f32x16 __attribute__((ext_vector_type(16)));
typedef int    i32x8  __attribute__((ext_vector_type(8)));
typedef unsigned char u8;

#define LOG2E  1.44269504f
#define QSCALE 0.18033688f      /* 0.125 * log2(e) */
#define WSC    16.0f            /* weight prescale before fp8 cast */
#define IWSC   0.0625f
#define QSTORE 0.36067376f      /* QSCALE * 32 / 16 : gemm-acc -> q_fp8 */
#define KSTORE 0.5f             /* 8 / 16          : gemm-acc -> k_fp8 */
#define SCALE_A_M8 0x77777777   /* e8m0 119 = 2^-8 (undo 32*8) */
#define SCALE_ONE  0x7F7F7F7F   /* e8m0 127 = 1.0 */

// ---------------------------------------------------------------- helpers
__device__ __forceinline__ void gld_lds16(const void* gptr, void* lptr) {
    __builtin_amdgcn_global_load_lds(
        (const __attribute__((address_space(1))) unsigned int*)gptr,
        (__attribute__((address_space(3))) unsigned int*)lptr,
        16, 0, 0);
}

// ---------------------------------------------------------------- merged cast + zero
// fp8 e4m3. blocks [0,6144): g (x1) ; [6144,6720): wq ; [6720,7296): wk ;
// [7296,9600): w_hn (weights x16). blocks [0,104) zero sums; block 0 zeroes out[0].
__global__ void cast_all(const float* __restrict__ g, const float* __restrict__ wq,
                         const float* __restrict__ wk, const float* __restrict__ whn,
                         u8* __restrict__ g_f8, u8* __restrict__ Wcat,
                         float* __restrict__ sums, float* __restrict__ out) {
    int b = blockIdx.x, t = threadIdx.x;
    if (b < 104) {
        float4 z = {0.f, 0.f, 0.f, 0.f};
        *(float4*)(sums + (b * 256 + t) * 4) = z;
        if (b == 0 && t == 0) out[0] = 0.f;
    }
    const float* src; u8* dst; int off; float sc;
    if (b < 6144)      { src = g;   dst = g_f8;           off = 0;    sc = 1.0f; }
    else if (b < 6720) { src = wq;  dst = Wcat;           off = 6144; sc = WSC;  }
    else if (b < 7296) { src = wk;  dst = Wcat + 589824;  off = 6720; sc = WSC;  }
    else               { src = whn; dst = Wcat + 1179648; off = 7296; sc = WSC;  }
    int i = ((b - off) * 256 + t) * 4;
    float4 v = *(const float4*)(src + i);
    int p = __builtin_amdgcn_cvt_pk_fp8_f32(sc * v.x, sc * v.y, 0, false);
    p     = __builtin_amdgcn_cvt_pk_fp8_f32(sc * v.z, sc * v.w, p, true);
    *(int*)(dst + i) = p;
}

// ---------------------------------------------------------------- fused NT GEMM (MX-fp8)
// C_full[M,4608] = A[M,768] * Wcat[4608,768]^T, fp8 e4m3, fp32 acc.
// mfma_scale_f32_16x16x128_f8f6f4, unit scales. BM=BN=128, BK=128.
// cols [0,1536): q/k -> fp8 qkh[b][h][{q,k}] planes (1024x64 B), SUPER-ROW swizzle:
//   u=kr>>1, sigma=(kr&1)*4+(z>>4), pos = u*128 + (sigma^(u&7))*16 + (z&15).
//   q scaled QSTORE, k scaled KSTORE.
// cols [1536,4608): Hopfield -> rowsum += exp2(beta*log2e/16 * acc) via atomicAdd.
__global__ void gemm_fused(const u8* __restrict__ A, const u8* __restrict__ Bm,
                           u8* __restrict__ qkh, float* __restrict__ rowsum,
                           const float* __restrict__ beta_p) {
    __shared__ __align__(16) u8 As[128 * 128];
    __shared__ __align__(16) u8 Bs[128 * 128];
    const int t = threadIdx.x;
    const int w = t >> 6, l = t & 63;
    const int wm = (w >> 1) * 64, wn = (w & 1) * 64;
    const int tile_m = blockIdx.x * 128;
    const int tile_n = blockIdx.y * 128;

    f32x4 acc[4][4];
#pragma unroll
    for (int i = 0; i < 4; i++)
#pragma unroll
        for (int j = 0; j < 4; j++)
#pragma unroll
            for (int q = 0; q < 4; q++) acc[i][j][q] = 0.f;

    const int srow = t >> 3;
    const int sswz = (t & 7) ^ (srow & 7);
    const u8* gA = A  + (size_t)(tile_m + srow) * 768 + sswz * 16;
    const u8* gB = Bm + (size_t)(tile_n + srow) * 768 + sswz * 16;

    const int fr = l & 15, fg = l >> 4;
    const int s0 = ((2 * fg)     ^ (fr & 7)) * 16;
    const int s1 = ((2 * fg + 1) ^ (fr & 7)) * 16;

    for (int k0 = 0; k0 < 768; k0 += 128) {
#pragma unroll
        for (int i = 0; i < 4; i++) {
            gld_lds16(gA + (size_t)i * 32 * 768 + k0, As + (i * 256 + t) * 16);
            gld_lds16(gB + (size_t)i * 32 * 768 + k0, Bs + (i * 256 + t) * 16);
        }
        __builtin_amdgcn_s_waitcnt(0);
        __syncthreads();

        union F8 { uint4 q[2]; i32x8 v; };
        i32x8 af[4], bfr[4];
#pragma unroll
        for (int i = 0; i < 4; i++) {
            const u8* ra = As + (wm + i * 16 + fr) * 128;
            const u8* rb = Bs + (wn + i * 16 + fr) * 128;
            F8 ua, ub;
            ua.q[0] = *(const uint4*)(ra + s0);
            ua.q[1] = *(const uint4*)(ra + s1);
            ub.q[0] = *(const uint4*)(rb + s0);
            ub.q[1] = *(const uint4*)(rb + s1);
            af[i] = ua.v; bfr[i] = ub.v;
        }
#pragma unroll
        for (int i = 0; i < 4; i++)
#pragma unroll
            for (int j = 0; j < 4; j++)
                acc[i][j] = __builtin_amdgcn_mfma_scale_f32_16x16x128_f8f6f4(
                    af[i], bfr[j], acc[i][j], 0, 0, 0, SCALE_ONE, 0, SCALE_ONE);
        __syncthreads();
    }

    const int cr = fg * 4, cc = fr;

    if (tile_n < 1536) {
        const int tt = (tile_n >= 768);
        const int hh = (tile_n - tt * 768 + wn) >> 6;
        const int bb = tile_m >> 10;
        const int m7 = tile_m & 1023;
        const float sc = tt ? KSTORE : QSTORE;
        u8* base = qkh + ((size_t)((bb * 12 + hh) * 2 + tt) << 16);
#pragma unroll
        for (int i = 0; i < 4; i++)
#pragma unroll
            for (int r = 0; r < 4; r++) {
                int kr = m7 + wm + i * 16 + cr + r;
                int u = kr >> 1, p4 = (kr & 1) * 4, u7 = u & 7;
                u8* rowp = base + (size_t)u * 128;
#pragma unroll
                for (int j = 0; j < 4; j++) {
                    int pv = __builtin_amdgcn_cvt_pk_fp8_f32(sc * acc[i][j][r], 0.f, 0, false);
                    rowp[((p4 + j) ^ u7) * 16 + cc] = (u8)(pv & 0xFF);
                }
            }
    } else {
        const float sc2 = beta_p[0] * LOG2E * IWSC;
#pragma unroll
        for (int i = 0; i < 4; i++)
#pragma unroll
            for (int r = 0; r < 4; r++) {
                float s = 0.f;
#pragma unroll
                for (int j = 0; j < 4; j++) s += __builtin_amdgcn_exp2f(sc2 * acc[i][j][r]);
                s += __shfl_xor(s, 1, 16);
                s += __shfl_xor(s, 2, 16);
                s += __shfl_xor(s, 4, 16);
                s += __shfl_xor(s, 8, 16);
                if ((l & 15) == 0)
                    atomicAdd(&rowsum[tile_m + wm + i * 16 + cr + r], s);
            }
    }
}

// ---------------------------------------------------------------- attention exp-sums
// qkh fp8 planes (super-row swizzled). grid (qt*2+kh:16, h:12, b:8), 256 thr.
// mfma_scale_f32_32x32x64_f8f6f4: whole Z=64 per instruction; scale_a = 2^-8
// folds stored q/k gains so acc = beta*log2e*(q.k) -> rs += exp2(acc) directly.
// launch_bounds (256,4) = 128-reg cap; nt-loop unroll 2 bounds acc/ub liveness
// (R8's unroll-4 under an 85-reg cap spilled: 2.55 GB scratch FETCH).
__global__ void __launch_bounds__(256, 4)
attn_energy(const u8* __restrict__ qkh, float* __restrict__ arow) {
    __shared__ __align__(16) u8 Sq[8192];
    __shared__ __align__(16) u8 Sk[2][8192];
    const int t = threadIdx.x, w = t >> 6, l = t & 63;
    const int qt = blockIdx.x >> 1, kh = blockIdx.x & 1;
    const int h = blockIdx.y, b = blockIdx.z;
    const u8* qp = qkh + ((size_t)((b * 12 + h) * 2 + 0) << 16) + qt * 8192;
    const u8* kp = qkh + ((size_t)((b * 12 + h) * 2 + 1) << 16) + kh * 32768;

    gld_lds16(qp + t * 16,        Sq + t * 16);
    gld_lds16(qp + 4096 + t * 16, Sq + 4096 + t * 16);
    gld_lds16(kp + t * 16,        Sk[0] + t * 16);
    gld_lds16(kp + 4096 + t * 16, Sk[0] + 4096 + t * 16);
    __builtin_amdgcn_s_waitcnt(0);
    __syncthreads();

    const int ln = l & 31, lh = l >> 5;
    union F8x32 { uint4 q[2]; i32x8 v; };

    const int rA = w * 32 + ln, uA = rA >> 1, u7A = uA & 7;
    const int sA = (rA & 1) * 4 + lh * 2;
    F8x32 ua;
    ua.q[0] = *(const uint4*)(Sq + uA * 128 + ((sA)     ^ u7A) * 16);
    ua.q[1] = *(const uint4*)(Sq + uA * 128 + ((sA + 1) ^ u7A) * 16);

    float rs[16];
#pragma unroll
    for (int r = 0; r < 16; r++) rs[r] = 0.f;

    for (int kc = 0; kc < 4; kc++) {
        const u8* Sc = Sk[kc & 1];
        __builtin_amdgcn_s_waitcnt(0);
        __syncthreads();
        if (kc < 3) {
            const u8* src = kp + (kc + 1) * 8192;
            u8* d = (u8*)Sk[1 - (kc & 1)];
            gld_lds16(src + t * 16,        d + t * 16);
            gld_lds16(src + 4096 + t * 16, d + 4096 + t * 16);
        }
#pragma unroll 2
        for (int nt = 0; nt < 4; nt++) {
            const int rB = nt * 32 + ln, uB = rB >> 1, u7B = uB & 7;
            const int sB = (rB & 1) * 4 + lh * 2;
            F8x32 ub;
            ub.q[0] = *(const uint4*)(Sc + uB * 128 + ((sB)     ^ u7B) * 16);
            ub.q[1] = *(const uint4*)(Sc + uB * 128 + ((sB + 1) ^ u7B) * 16);
            f32x16 acc;
#pragma unroll
            for (int q = 0; q < 16; q++) acc[q] = 0.f;
            acc = __builtin_amdgcn_mfma_scale_f32_32x32x64_f8f6f4(
                ua.v, ub.v, acc, 0, 0, 0, SCALE_A_M8, 0, SCALE_ONE);
#pragma unroll
            for (int r = 0; r < 16; r++) rs[r] += __builtin_amdgcn_exp2f(acc[r]);
        }
    }

    // D layout (32x32): col=lane&31 (k-col), row=(r&3)+8*(r>>2)+4*lh (q-row).
    const int rowbase = (b * 12 + h) * 1024 + qt * 128 + w * 32 + lh * 4;
#pragma unroll
    for (int r = 0; r < 16; r++) {
        float v = rs[r];
        v += __shfl_xor(v, 1, 32);
        v += __shfl_xor(v, 2, 32);
        v += __shfl_xor(v, 4, 32);
        v += __shfl_xor(v, 8, 32);
        v += __shfl_xor(v, 16, 32);
        if (ln == 0)
            atomicAdd(&arow[rowbase + (r & 3) + 8 * (r >> 2)], v);
    }
}

// ---------------------------------------------------------------- merged finalize
__global__ void finalize(const float* __restrict__ sums, const float* __restrict__ beta_p,
                         float* __restrict__ out) {
    __shared__ float wpart[4];
    const int t = threadIdx.x, w = t >> 6, l = t & 63;
    const int i = blockIdx.x * 256 + t;
    float v;
    if (i < 8192) v = (-1.f / beta_p[0]) * __logf(sums[i]);
    else          v = -8.f * __logf(sums[i]);
    for (int o = 32; o > 0; o >>= 1) v += __shfl_down(v, o, 64);
    if (l == 0) wpart[w] = v;
    __syncthreads();
    if (t == 0) atomicAdd(out, wpart[0] + wpart[1] + wpart[2] + wpart[3]);
}

// ---------------------------------------------------------------- launch
extern "C" void kernel_launch(void* const* d_in, const int* in_sizes, int n_in,
                              void* d_out, int out_size, void* d_ws, size_t ws_size,
                              hipStream_t stream) {
    const float* g    = (const float*)d_in[0];
    const float* wq   = (const float*)d_in[1];
    const float* wk   = (const float*)d_in[2];
    const float* w_hn = (const float*)d_in[3];
    const float* beta = (const float*)d_in[4];
    float* out = (float*)d_out;

    char* ws = (char*)d_ws;
    u8*    g_f8   = (u8*)(ws);                    //  6,291,456 B
    u8*    Wcat   = (u8*)(ws + 6291456);          //  3,538,944 B
    u8*    qkh    = (u8*)(ws + 9830400);          // 12,582,912 B [8][12][2] 64KB planes
    float* sums   = (float*)(ws + 22413312);      // rowsum 8192 | arow 98304
    float* rowsum = sums;
    float* arow   = sums + 8192;

    cast_all<<<9600, 256, 0, stream>>>(g, wq, wk, w_hn, g_f8, Wcat, sums, out);

    dim3 gg(64, 36);
    gemm_fused<<<gg, 256, 0, stream>>>(g_f8, Wcat, qkh, rowsum, beta);

    dim3 ga(16, 12, 8);   // (qt,kh), h, b
    attn_energy<<<ga, 256, 0, stream>>>(qkh, arow);

    finalize<<<416, 256, 0, stream>>>(sums, beta, out);
}